// Round 4
// baseline (507.329 us; speedup 1.0000x reference)
//
#include <hip/hip_runtime.h>
#include <hip/hip_fp16.h>
#include <math.h>

// ---------------------------------------------------------------------------
// FeedForward: LN -> act-int8-fakequant x ternary-weight qlinear -> GELU(erf)
//              -> qlinear.  Exact-integer i8 MFMA GEMMs (32x32x32).
// h1/h2 fp16 -> exact per-tensor quantile via 32768-bin |bits| histogram.
// GEMM K-loop: register-staged prefetch (plain global loads -> VGPR ->
// ds_write), so s_barrier needs no vmcnt(0) drain (loads fly across it).
// Shapes: x[16384,1024], w1[4096,1024], w2[1024,4096], out[16384,1024] fp32.
// ---------------------------------------------------------------------------

#define M_ROWS 16384
#define D_DIM  1024
#define H_DIM  4096

typedef int i32x4 __attribute__((ext_vector_type(4)));
typedef int i32x16 __attribute__((ext_vector_type(16)));

// ---------------------------------------------------------------------------
// LayerNorm: one block (256 thr) per row of 1024; fp16 output.
// ---------------------------------------------------------------------------
__device__ __forceinline__ float block_sum256(float v, float* lds) {
#pragma unroll
  for (int o = 32; o > 0; o >>= 1) v += __shfl_down(v, o, 64);
  int t = threadIdx.x;
  __syncthreads();
  if ((t & 63) == 0) lds[t >> 6] = v;
  __syncthreads();
  return lds[0] + lds[1] + lds[2] + lds[3];
}

__global__ __launch_bounds__(256) void k_layernorm(
    const float* __restrict__ x, const float* __restrict__ g,
    const float* __restrict__ b, __half* __restrict__ out) {
  __shared__ float lds[4];
  int row = blockIdx.x, t = threadIdx.x;
  float4 v = ((const float4*)(x + (size_t)row * D_DIM))[t];
  float s = v.x + v.y + v.z + v.w;
  s = block_sum256(s, lds);
  float mu = s * (1.0f / D_DIM);
  float d0 = v.x - mu, d1 = v.y - mu, d2 = v.z - mu, d3 = v.w - mu;
  float ss = d0 * d0 + d1 * d1 + d2 * d2 + d3 * d3;
  ss = block_sum256(ss, lds);
  float inv = 1.0f / sqrtf(ss * (1.0f / D_DIM) + 1e-5f);
  float4 gg = ((const float4*)g)[t];
  float4 bb = ((const float4*)b)[t];
  __half2 p0 = __floats2half2_rn(d0 * inv * gg.x + bb.x, d1 * inv * gg.y + bb.y);
  __half2 p1 = __floats2half2_rn(d2 * inv * gg.z + bb.z, d3 * inv * gg.w + bb.w);
  uint2 st;
  st.x = *(unsigned*)&p0;
  st.y = *(unsigned*)&p1;
  ((uint2*)(out + (size_t)row * D_DIM))[t] = st;
}

// ---------------------------------------------------------------------------
// Weight ternary quantization (both weights per launch)
// ---------------------------------------------------------------------------
__global__ __launch_bounds__(256) void k_absmean2(const float4* __restrict__ w1,
                                                  const float4* __restrict__ w2,
                                                  size_t n4, double* __restrict__ out) {
  int which = (blockIdx.x >= (gridDim.x >> 1)) ? 1 : 0;
  const float4* p = which ? w2 : w1;
  unsigned half_grid = gridDim.x >> 1;
  unsigned blk = blockIdx.x - which * half_grid;
  double s = 0.0;
  size_t stride = (size_t)half_grid * blockDim.x;
  for (size_t i = (size_t)blk * blockDim.x + threadIdx.x; i < n4; i += stride) {
    float4 v = p[i];
    s += (double)fabsf(v.x) + (double)fabsf(v.y) + (double)fabsf(v.z) + (double)fabsf(v.w);
  }
#pragma unroll
  for (int o = 32; o > 0; o >>= 1) s += __shfl_down(s, o, 64);
  __shared__ double ds[4];
  int t = threadIdx.x;
  if ((t & 63) == 0) ds[t >> 6] = s;
  __syncthreads();
  if (t == 0) atomicAdd(out + which, ds[0] + ds[1] + ds[2] + ds[3]);
}

__device__ __forceinline__ int tern1(float w, float gamma) {
  return (int)fminf(1.f, fmaxf(-1.f, rintf(w / gamma)));
}

__global__ __launch_bounds__(256) void k_wquant2(const float4* __restrict__ w1,
                                                 const float4* __restrict__ w2,
                                                 unsigned* __restrict__ q1,
                                                 unsigned* __restrict__ q2, size_t n4,
                                                 const double* __restrict__ sump,
                                                 double inv_n, float* __restrict__ gamma_out) {
  int which = (blockIdx.x >= (gridDim.x >> 1)) ? 1 : 0;
  const float4* w = which ? w2 : w1;
  unsigned* wq = which ? q2 : q1;
  unsigned half_grid = gridDim.x >> 1;
  unsigned blk = blockIdx.x - which * half_grid;
  float gamma = (float)(sump[which] * inv_n) + 1e-5f;
  if (blk == 0 && threadIdx.x == 0) gamma_out[which] = gamma;
  size_t stride = (size_t)half_grid * blockDim.x;
  for (size_t i = (size_t)blk * blockDim.x + threadIdx.x; i < n4; i += stride) {
    float4 v = w[i];
    int a = tern1(v.x, gamma), b = tern1(v.y, gamma), c = tern1(v.z, gamma), d = tern1(v.w, gamma);
    wq[i] = (unsigned)(a & 255) | ((unsigned)(b & 255) << 8) |
            ((unsigned)(c & 255) << 16) | ((unsigned)(d & 255) << 24);
  }
}

// ---------------------------------------------------------------------------
// Exact fp16 quantile: 32768-bin histogram over |bits| (monotone for halfs).
// 1024 threads (16 waves/CU -> 2x atomic issue width + latency hiding vs 512).
// ---------------------------------------------------------------------------
__global__ __launch_bounds__(1024) void k_hist16(const uint4* __restrict__ p, size_t n8,
                                                 unsigned* __restrict__ hist) {
  extern __shared__ unsigned h[];  // 32768 bins
  int t = threadIdx.x;
  for (int i = t; i < 32768; i += 1024) h[i] = 0;
  __syncthreads();
  size_t stride = (size_t)gridDim.x * 1024;
  for (size_t i = (size_t)blockIdx.x * 1024 + t; i < n8; i += stride) {
    uint4 u = p[i];
    atomicAdd(&h[u.x & 0x7FFFu], 1u);
    atomicAdd(&h[(u.x >> 16) & 0x7FFFu], 1u);
    atomicAdd(&h[u.y & 0x7FFFu], 1u);
    atomicAdd(&h[(u.y >> 16) & 0x7FFFu], 1u);
    atomicAdd(&h[u.z & 0x7FFFu], 1u);
    atomicAdd(&h[(u.z >> 16) & 0x7FFFu], 1u);
    atomicAdd(&h[u.w & 0x7FFFu], 1u);
    atomicAdd(&h[(u.w >> 16) & 0x7FFFu], 1u);
  }
  __syncthreads();
  for (int i = t; i < 32768; i += 1024) {
    unsigned c = h[i];
    if (c) atomicAdd(&hist[i], c);
  }
}

// scan 32768 bins; order stats a[k], a[k+1]; numpy lerp -> amax, scale
__global__ __launch_bounds__(256) void k_scanq(const unsigned* __restrict__ hist,
                                               float* __restrict__ scl,
                                               unsigned long long k, double frac) {
  __shared__ unsigned tsum[256];
  __shared__ unsigned long long pre[256];
  __shared__ unsigned vk, vk1;
  int t = threadIdx.x;
  unsigned s = 0;
  for (int j = 0; j < 128; ++j) s += hist[t * 128 + j];
  tsum[t] = s;
  __syncthreads();
  if (t == 0) {
    unsigned long long c = 0;
    for (int i = 0; i < 256; ++i) { pre[i] = c; c += tsum[i]; }
  }
  __syncthreads();
  unsigned long long base = pre[t];
  for (int j = 0; j < 128; ++j) {
    unsigned c = hist[t * 128 + j];
    if (base <= k && k < base + c) vk = t * 128 + j;
    if (base <= k + 1 && k + 1 < base + c) vk1 = t * 128 + j;
    base += c;
  }
  __syncthreads();
  if (t == 0) {
    double a = (double)__half2float(__ushort_as_half((unsigned short)vk));
    double b = (double)__half2float(__ushort_as_half((unsigned short)vk1));
    double qv = (frac >= 0.5) ? (b - (b - a) * (1.0 - frac)) : (a + (b - a) * frac);
    float amax = fmaxf((float)qv, 1e-5f);
    scl[0] = amax;
    scl[1] = 127.0f / amax;
  }
}

// ---------------------------------------------------------------------------
// Activation int8 quantization (fp16 source, 8 at a time)
// ---------------------------------------------------------------------------
__device__ __forceinline__ void unpack8(uint4 u, float* f) {
  __half2 h;
  h = *(__half2*)&u.x; f[0] = __low2float(h); f[1] = __high2float(h);
  h = *(__half2*)&u.y; f[2] = __low2float(h); f[3] = __high2float(h);
  h = *(__half2*)&u.z; f[4] = __low2float(h); f[5] = __high2float(h);
  h = *(__half2*)&u.w; f[6] = __low2float(h); f[7] = __high2float(h);
}

__device__ __forceinline__ unsigned qpack4(float a, float b, float c, float d, float s) {
  int qa = (int)fminf(127.f, fmaxf(-128.f, rintf(a * s)));
  int qb = (int)fminf(127.f, fmaxf(-128.f, rintf(b * s)));
  int qc = (int)fminf(127.f, fmaxf(-128.f, rintf(c * s)));
  int qd = (int)fminf(127.f, fmaxf(-128.f, rintf(d * s)));
  return (unsigned)(qa & 255) | ((unsigned)(qb & 255) << 8) |
         ((unsigned)(qc & 255) << 16) | ((unsigned)(qd & 255) << 24);
}

__global__ __launch_bounds__(256) void k_quant16(const uint4* __restrict__ p,
                                                 uint2* __restrict__ q, size_t n8,
                                                 const float* __restrict__ scl) {
  float s = scl[1];
  size_t stride = (size_t)gridDim.x * blockDim.x;
  for (size_t i = (size_t)blockIdx.x * blockDim.x + threadIdx.x; i < n8; i += stride) {
    float f[8];
    unpack8(p[i], f);
    uint2 r;
    r.x = qpack4(f[0], f[1], f[2], f[3], s);
    r.y = qpack4(f[4], f[5], f[6], f[7], s);
    q[i] = r;
  }
}

// ---------------------------------------------------------------------------
// GELU via Abramowitz-Stegun 7.1.26 erf (abs err 1.5e-7)
// ---------------------------------------------------------------------------
__device__ __forceinline__ float gelu_fast(float v) {
  float a = fabsf(v) * 0.70710678118654752f;
  float t = __builtin_amdgcn_rcpf(fmaf(0.3275911f, a, 1.0f));
  float p = t * fmaf(t, fmaf(t, fmaf(t, fmaf(t, 1.061405429f, -1.453152027f),
                                     1.421413741f), -0.284496736f), 0.254829592f);
  float e = __expf(-a * a);
  float er = fmaf(-p, e, 1.0f);
  float erf_s = copysignf(er, v);
  return 0.5f * v * (1.0f + erf_s);
}

// ---------------------------------------------------------------------------
// int8 GEMM, C = A[M,K] * B[N,K]^T.  128x128 tile, BK=64 (8KB+8KB LDS),
// register-staged prefetch: plain global_load_dwordx4 -> VGPR -> ds_write.
// Barriers then only wait lgkmcnt (LDS); chunk k+1's global loads stay in
// flight across both barriers and the whole compute phase (m97's vmcnt(0)
// drain eliminated).  LDS layout granule-major with +2g row rotation:
//   addr(row, g) = g*2048 + ((row + 2g) & 127) * 16
// -> frag ds_read_b128 runs are contiguous 512B per half-wave (zero-conflict
// m97 pattern); staged writes hit all 8 bank groups.  4 waves, each 2x2 of
// 32x32x32 i8 MFMAs.
// ---------------------------------------------------------------------------
template <int K, bool GELU>
__global__ __launch_bounds__(256, 4) void k_gemm(const signed char* __restrict__ A,
                                                 const signed char* __restrict__ B,
                                                 int N, void* __restrict__ outp,
                                                 const float* __restrict__ gamma_p,
                                                 const float* __restrict__ scl) {
  __shared__ __align__(16) signed char As[8192];
  __shared__ __align__(16) signed char Bs[8192];
  const int t = threadIdx.x;
  const int l = t & 63;
  const int wv = t >> 6;
  const int wr = (wv >> 1) * 64, wc = (wv & 1) * 64;
  const int m0 = blockIdx.y * 128, n0 = blockIdx.x * 128;

  // staging slots s in {t, t+256}: row = s>>2, g = s&3 (4 lanes = 64B coalesced)
  const signed char* ga[2]; const signed char* gb[2];
  int lw[2];
#pragma unroll
  for (int p = 0; p < 2; ++p) {
    int s = p * 256 + t;
    int row = s >> 2, g = s & 3;
    ga[p] = A + (size_t)(m0 + row) * K + g * 16;
    gb[p] = B + (size_t)(n0 + row) * K + g * 16;
    lw[p] = g * 2048 + (((row + 2 * g) & 127) << 4);
  }

  // fragment read offsets: row = w? + i*32 + (l&31), g = 2*ks + (l>>5)
  int a_off[2][2], b_off[2][2];
#pragma unroll
  for (int i = 0; i < 2; ++i)
#pragma unroll
    for (int ks = 0; ks < 2; ++ks) {
      int g = 2 * ks + (l >> 5);
      int am = wr + i * 32 + (l & 31);
      a_off[i][ks] = g * 2048 + (((am + 2 * g) & 127) << 4);
      int bn = wc + i * 32 + (l & 31);
      b_off[i][ks] = g * 2048 + (((bn + 2 * g) & 127) << 4);
    }

  i32x16 acc[2][2];
#pragma unroll
  for (int mi = 0; mi < 2; ++mi)
#pragma unroll
    for (int ni = 0; ni < 2; ++ni)
      acc[mi][ni] = (i32x16)(0);

  uint4 pa0, pa1, pb0, pb1;
  pa0 = *(const uint4*)(ga[0]);
  pa1 = *(const uint4*)(ga[1]);
  pb0 = *(const uint4*)(gb[0]);
  pb1 = *(const uint4*)(gb[1]);

  auto compute = [&]() {
#pragma unroll
    for (int ks = 0; ks < 2; ++ks) {
      i32x4 af[2], bf[2];
#pragma unroll
      for (int i = 0; i < 2; ++i) af[i] = *(const i32x4*)(As + a_off[i][ks]);
#pragma unroll
      for (int i = 0; i < 2; ++i) bf[i] = *(const i32x4*)(Bs + b_off[i][ks]);
#pragma unroll
      for (int mi = 0; mi < 2; ++mi)
#pragma unroll
        for (int ni = 0; ni < 2; ++ni)
          acc[mi][ni] = __builtin_amdgcn_mfma_i32_32x32x32_i8(af[mi], bf[ni], acc[mi][ni], 0, 0, 0);
    }
  };

  for (int kk = 0; kk < K - 64; kk += 64) {
    __syncthreads();                       // previous chunk's ds_reads done
    *(uint4*)(As + lw[0]) = pa0;
    *(uint4*)(As + lw[1]) = pa1;
    *(uint4*)(Bs + lw[0]) = pb0;
    *(uint4*)(Bs + lw[1]) = pb1;
    // prefetch chunk kk+64: loads stay in flight across the barrier + MFMAs
    pa0 = *(const uint4*)(ga[0] + kk + 64);
    pa1 = *(const uint4*)(ga[1] + kk + 64);
    pb0 = *(const uint4*)(gb[0] + kk + 64);
    pb1 = *(const uint4*)(gb[1] + kk + 64);
    __syncthreads();                       // ds_writes visible (lgkmcnt only)
    compute();
  }
  __syncthreads();
  *(uint4*)(As + lw[0]) = pa0;
  *(uint4*)(As + lw[1]) = pa1;
  *(uint4*)(Bs + lw[0]) = pb0;
  *(uint4*)(Bs + lw[1]) = pb1;
  __syncthreads();
  compute();

  // dequant: xq = n/s, wq = m*gamma -> contribution (gamma/s) * (n·m)
  // C/D layout (32x32): col = lane&31, row = (reg&3) + 8*(reg>>2) + 4*(lane>>5)
  const float cs = (*gamma_p) / scl[1];
  const int col0 = n0 + wc + (l & 31);
  const int row0 = m0 + wr + 4 * (l >> 5);
#pragma unroll
  for (int mi = 0; mi < 2; ++mi) {
#pragma unroll
    for (int ni = 0; ni < 2; ++ni) {
      int col = col0 + ni * 32;
#pragma unroll
      for (int reg = 0; reg < 16; ++reg) {
        int row = row0 + mi * 32 + (reg & 3) + 8 * (reg >> 2);
        float v = cs * (float)acc[mi][ni][reg];
        size_t idx = (size_t)row * N + col;
        if (GELU) {
          ((__half*)outp)[idx] = __float2half(gelu_fast(v));
        } else {
          ((float*)outp)[idx] = v;
        }
      }
    }
  }
}

// ---------------------------------------------------------------------------
// Launcher.  Workspace layout (MB):
//   [0,128):   h2 fp16          [128,160): h1 fp16 (dead after GEMM1)
//   [160,176): xq1              [128,192): xq2 (reuses h1+xq1 after GEMM1)
//   [192,196): w1q  [196,200): w2q
//   [200,+):   hista 128K, histb 128K, wsum[2] dbl, gamma[2] f32, scl pairs
// ---------------------------------------------------------------------------
extern "C" void kernel_launch(void* const* d_in, const int* in_sizes, int n_in,
                              void* d_out, int out_size, void* d_ws, size_t ws_size,
                              hipStream_t stream) {
  const float* x = (const float*)d_in[0];
  const float* ln_g = (const float*)d_in[1];
  const float* ln_b = (const float*)d_in[2];
  const float* w1 = (const float*)d_in[3];
  const float* w2 = (const float*)d_in[4];
  float* out = (float*)d_out;

  char* ws = (char*)d_ws;
  __half* h2 = (__half*)ws;
  __half* h1 = (__half*)(ws + ((size_t)128 << 20));
  signed char* xq1 = (signed char*)(ws + ((size_t)160 << 20));
  signed char* xq2 = (signed char*)(ws + ((size_t)128 << 20));
  signed char* w1q = (signed char*)(ws + ((size_t)192 << 20));
  signed char* w2q = (signed char*)(ws + ((size_t)196 << 20));
  char* sm = ws + ((size_t)200 << 20);
  unsigned* hista = (unsigned*)sm;
  unsigned* histb = (unsigned*)(sm + (128 << 10));
  double* wsum = (double*)(sm + (256 << 10));
  float* gamma = (float*)(sm + (256 << 10) + 16);
  float* scl1 = (float*)(sm + (256 << 10) + 32);
  float* scl2 = (float*)(sm + (256 << 10) + 40);

  hipMemsetAsync(sm, 0, (256 << 10) + 64, stream);
  hipFuncSetAttribute((const void*)k_hist16, hipFuncAttributeMaxDynamicSharedMemorySize,
                      131072);

  const double qq = 1.0 - 0.005;
  const unsigned long long N1 = (unsigned long long)M_ROWS * D_DIM;
  const unsigned long long N2 = (unsigned long long)M_ROWS * H_DIM;
  double idx1 = qq * (double)(N1 - 1);
  double idx2 = qq * (double)(N2 - 1);
  unsigned long long k1 = (unsigned long long)idx1;
  unsigned long long k2 = (unsigned long long)idx2;
  double frac1 = idx1 - (double)k1;
  double frac2 = idx2 - (double)k2;

  const size_t nW4 = (size_t)H_DIM * D_DIM / 4;
  const double inv_nW = 1.0 / (double)(H_DIM * D_DIM);

  // ---- weights ----
  k_absmean2<<<1024, 256, 0, stream>>>((const float4*)w1, (const float4*)w2, nW4, wsum);
  k_wquant2<<<2048, 256, 0, stream>>>((const float4*)w1, (const float4*)w2,
                                      (unsigned*)w1q, (unsigned*)w2q, nW4, wsum, inv_nW, gamma);

  // ---- layernorm -> h1 fp16 ----
  k_layernorm<<<M_ROWS, 256, 0, stream>>>(x, ln_g, ln_b, h1);

  // ---- quantile 1 + quantize ----
  const size_t n8_1 = N1 / 8;
  k_hist16<<<256, 1024, 131072, stream>>>((const uint4*)h1, n8_1, hista);
  k_scanq<<<1, 256, 0, stream>>>(hista, scl1, k1, frac1);
  k_quant16<<<1024, 256, 0, stream>>>((const uint4*)h1, (uint2*)xq1, n8_1, scl1);

  // ---- GEMM1: [16384,1024] x [4096,1024]^T -> gelu -> h2 fp16 ----
  k_gemm<D_DIM, true><<<dim3(H_DIM / 128, M_ROWS / 128), 256, 0, stream>>>(
      xq1, w1q, H_DIM, (void*)h2, gamma + 0, scl1);

  // ---- quantile 2 + quantize ----
  const size_t n8_2 = N2 / 8;
  k_hist16<<<256, 1024, 131072, stream>>>((const uint4*)h2, n8_2, histb);
  k_scanq<<<1, 256, 0, stream>>>(histb, scl2, k2, frac2);
  k_quant16<<<2048, 256, 0, stream>>>((const uint4*)h2, (uint2*)xq2, n8_2, scl2);

  // ---- GEMM2: [16384,4096] x [1024,4096]^T -> out fp32 ----
  k_gemm<H_DIM, false><<<dim3(D_DIM / 128, M_ROWS / 128), 256, 0, stream>>>(
      xq2, w2q, D_DIM, (void*)out, gamma + 1, scl2);
}